// Round 1
// baseline (1642.372 us; speedup 1.0000x reference)
//
#include <hip/hip_runtime.h>
#include <hip/hip_bf16.h>

#define NN 50000
#define NE 600000
#define HIDC 128
#define NH 8
#define DH 16

typedef unsigned short u16;
typedef __attribute__((ext_vector_type(8))) short bf16x8;
typedef __attribute__((ext_vector_type(4))) float f32x4;

static __device__ __forceinline__ float bf2f(u16 u) {
    unsigned int x = ((unsigned int)u) << 16;
    return __uint_as_float(x);
}
static __device__ __forceinline__ u16 f2bf(float f) {
    unsigned int x = __float_as_uint(f);
    unsigned int r = (x + 0x7fffu + ((x >> 16) & 1u)) >> 16;
    return (u16)r;
}
static __device__ __forceinline__ void split2(float v, u16& h, u16& l) {
    h = f2bf(v);
    l = f2bf(v - bf2f(h));
}

// ---------------- CSR build ----------------
__global__ void k_init(int* deg, int* cursor) {
    int i = blockIdx.x * blockDim.x + threadIdx.x;
    if (i < NN) { deg[i] = 0; cursor[i] = 0; }
}

__global__ void k_count(const int* __restrict__ ei, int* __restrict__ deg) {
    int e = blockIdx.x * blockDim.x + threadIdx.x;
    if (e < NE) atomicAdd(&deg[ei[e]], 1);
}

// single-block scan, 1024 threads, 4 elems/thread/chunk, shfl-based
__global__ void k_scan(const int* __restrict__ deg, int* __restrict__ rowstart) {
    __shared__ int warpsum[16];
    __shared__ int chunkcarry;
    int t = threadIdx.x;
    int lane = t & 63, w = t >> 6;
    if (t == 0) { chunkcarry = 0; rowstart[0] = 0; }
    __syncthreads();
    for (int base = 0; base < NN; base += 4096) {
        int idx = base + t * 4;
        int v0 = (idx + 0 < NN) ? deg[idx + 0] : 0;
        int v1 = (idx + 1 < NN) ? deg[idx + 1] : 0;
        int v2 = (idx + 2 < NN) ? deg[idx + 2] : 0;
        int v3 = (idx + 3 < NN) ? deg[idx + 3] : 0;
        int s0 = v0, s1 = s0 + v1, s2 = s1 + v2, s3 = s2 + v3;
        int tot = s3;
        int sc = tot;
#pragma unroll
        for (int off = 1; off < 64; off <<= 1) {
            int u = __shfl_up(sc, off);
            if (lane >= off) sc += u;
        }
        if (lane == 63) warpsum[w] = sc;
        __syncthreads();
        int wpre = 0;
        for (int i = 0; i < w; i++) wpre += warpsum[i];
        int carry = chunkcarry;
        __syncthreads();
        int pre = carry + wpre + (sc - tot);
        if (idx + 0 < NN) rowstart[idx + 1] = pre + s0;
        if (idx + 1 < NN) rowstart[idx + 2] = pre + s1;
        if (idx + 2 < NN) rowstart[idx + 3] = pre + s2;
        if (idx + 3 < NN) rowstart[idx + 4] = pre + s3;
        if (t == 1023) chunkcarry = carry + wpre + sc;
        __syncthreads();
    }
}

__global__ void k_fill(const int* __restrict__ ei, const int* __restrict__ rowstart,
                       int* __restrict__ cursor, int* __restrict__ csr) {
    int e = blockIdx.x * blockDim.x + threadIdx.x;
    if (e < NE) {
        int d = ei[e];
        int slot = atomicAdd(&cursor[d], 1);
        csr[rowstart[d] + slot] = e;
    }
}

// ---------------- MFMA GEMM: C[M x NC] = A[M x K] @ W[K x NC] (+bias)(+relu)
// fp32 inputs, bf16 hi/lo split, 3 MFMA passes (~fp32 accuracy).
// BM=64, 256 thr = 4 waves (2x2). LDS in fragment order [tile][lane][8].
template <int NC, int K, bool RELU>
__global__ __launch_bounds__(256) void k_gemm(const float* __restrict__ A,
                                              const float* __restrict__ W,
                                              const float* __restrict__ bias,
                                              float* __restrict__ C, int M) {
    constexpr int NCT_W = NC / 32;  // coltiles per wave
    __shared__ __align__(16) u16 Ah[4 * 64 * 8], Al[4 * 64 * 8];
    __shared__ __align__(16) u16 Bh[(NC / 16) * 64 * 8], Bl[(NC / 16) * 64 * 8];

    const int t = threadIdx.x;
    const int lane = t & 63, wid = t >> 6;
    const int wr = wid >> 1, wc = wid & 1;
    const int c15 = lane & 15, lg = lane >> 4;
    const int row0 = blockIdx.x * 64;

    f32x4 acc[2][NCT_W];
#pragma unroll
    for (int m = 0; m < 2; m++)
#pragma unroll
        for (int n = 0; n < NCT_W; n++) acc[m][n] = (f32x4){0.f, 0.f, 0.f, 0.f};

    for (int k0 = 0; k0 < K; k0 += 32) {
        // stage A: 64 rows x 32 k, split to hi/lo, fragment order
#pragma unroll
        for (int i = 0; i < 2; i++) {
            int fl = t * 2 + i;
            int r = fl >> 3, k4 = fl & 7;
            float4 v = make_float4(0.f, 0.f, 0.f, 0.f);
            int row = row0 + r;
            if (row < M) v = *(const float4*)(A + (size_t)row * K + k0 + k4 * 4);
            int base = ((r >> 4) * 64 + (r & 15) + ((k4 >> 1) << 4)) * 8 + (k4 & 1) * 4;
            u16 hx, lx, hy, ly, hz, lz, hw, lw;
            split2(v.x, hx, lx); split2(v.y, hy, ly);
            split2(v.z, hz, lz); split2(v.w, hw, lw);
            ushort4 ph; ph.x = hx; ph.y = hy; ph.z = hz; ph.w = hw;
            ushort4 pl; pl.x = lx; pl.y = ly; pl.z = lz; pl.w = lw;
            *(ushort4*)&Ah[base] = ph;
            *(ushort4*)&Al[base] = pl;
        }
        // stage B: W rows k0..k0+31, all NC cols; 4x4 blocks per thread
#pragma unroll
        for (int hb = 0; hb < NC / 128; hb++) {
            int kb = (t >> 5) * 4;
            int c0 = hb * 128 + (t & 31) * 4;
            const float* wp = W + (size_t)(k0 + kb) * NC + c0;
            float4 w0 = *(const float4*)(wp);
            float4 w1 = *(const float4*)(wp + NC);
            float4 w2 = *(const float4*)(wp + 2 * NC);
            float4 w3 = *(const float4*)(wp + 3 * NC);
#pragma unroll
            for (int j = 0; j < 4; j++) {
                float e0 = j == 0 ? w0.x : j == 1 ? w0.y : j == 2 ? w0.z : w0.w;
                float e1 = j == 0 ? w1.x : j == 1 ? w1.y : j == 2 ? w1.z : w1.w;
                float e2 = j == 0 ? w2.x : j == 1 ? w2.y : j == 2 ? w2.z : w2.w;
                float e3 = j == 0 ? w3.x : j == 1 ? w3.y : j == 2 ? w3.z : w3.w;
                int c = c0 + j;
                int base = ((c >> 4) * 64 + (c & 15) + ((kb >> 3) << 4)) * 8 + (kb & 4);
                u16 h0, l0, h1, l1, h2, l2, h3, l3;
                split2(e0, h0, l0); split2(e1, h1, l1);
                split2(e2, h2, l2); split2(e3, h3, l3);
                ushort4 ph; ph.x = h0; ph.y = h1; ph.z = h2; ph.w = h3;
                ushort4 pl; pl.x = l0; pl.y = l1; pl.z = l2; pl.w = l3;
                *(ushort4*)&Bh[base] = ph;
                *(ushort4*)&Bl[base] = pl;
            }
        }
        __syncthreads();
        bf16x8 ah[2], alo[2];
#pragma unroll
        for (int m = 0; m < 2; m++) {
            int rt = wr * 2 + m;
            ah[m] = *(const bf16x8*)&Ah[(rt * 64 + lane) * 8];
            alo[m] = *(const bf16x8*)&Al[(rt * 64 + lane) * 8];
        }
#pragma unroll
        for (int n = 0; n < NCT_W; n++) {
            int ct = wc * NCT_W + n;
            bf16x8 bh = *(const bf16x8*)&Bh[(ct * 64 + lane) * 8];
            bf16x8 bl = *(const bf16x8*)&Bl[(ct * 64 + lane) * 8];
#pragma unroll
            for (int m = 0; m < 2; m++) {
                acc[m][n] = __builtin_amdgcn_mfma_f32_16x16x32_bf16(ah[m], bh, acc[m][n], 0, 0, 0);
                acc[m][n] = __builtin_amdgcn_mfma_f32_16x16x32_bf16(ah[m], bl, acc[m][n], 0, 0, 0);
                acc[m][n] = __builtin_amdgcn_mfma_f32_16x16x32_bf16(alo[m], bh, acc[m][n], 0, 0, 0);
            }
        }
        __syncthreads();
    }
    // epilogue: D col = lane&15, row = 4*(lane>>4)+reg
#pragma unroll
    for (int m = 0; m < 2; m++) {
        int rbase = row0 + wr * 32 + m * 16 + lg * 4;
#pragma unroll
        for (int n = 0; n < NCT_W; n++) {
            int col = wc * (NCT_W * 16) + n * 16 + c15;
            float bv = bias ? bias[col] : 0.f;
#pragma unroll
            for (int r = 0; r < 4; r++) {
                int row = rbase + r;
                if (row < M) {
                    float o = acc[m][n][r] + bv;
                    if (RELU) o = fmaxf(o, 0.f);
                    C[(size_t)row * NC + col] = o;
                }
            }
        }
    }
}

// ---------------- fused edge pre (MFMA): Eh = conn@WE (K=128, NC=256), epilogue:
// conn_e = relu(signed_sqrt((Qh[dst]+Kh[src])*Ew)+Eb) -> bf16; clamped score per head.
// wave (wr,wc): rows wr*32+m*16, Ew coltiles wc*4+n, Eb coltiles 8+wc*4+n (paired).
__global__ __launch_bounds__(256) void k_edge_pre(
    const float* __restrict__ conn, const float* __restrict__ WE,
    const float* __restrict__ Qh, const float* __restrict__ Kh,
    const int* __restrict__ ei, const float* __restrict__ Aw,
    u16* __restrict__ conn_e, float* __restrict__ scoreraw) {
    __shared__ __align__(16) u16 Ah[4 * 64 * 8], Al[4 * 64 * 8];
    __shared__ __align__(16) u16 Bh[16 * 64 * 8], Bl[16 * 64 * 8];
    const int t = threadIdx.x;
    const int lane = t & 63, wid = t >> 6;
    const int wr = wid >> 1, wc = wid & 1;
    const int c15 = lane & 15, lg = lane >> 4;
    const int row0 = blockIdx.x * 64;

    f32x4 acc[2][8];
#pragma unroll
    for (int m = 0; m < 2; m++)
#pragma unroll
        for (int n = 0; n < 8; n++) acc[m][n] = (f32x4){0.f, 0.f, 0.f, 0.f};

    for (int k0 = 0; k0 < 128; k0 += 32) {
#pragma unroll
        for (int i = 0; i < 2; i++) {
            int fl = t * 2 + i;
            int r = fl >> 3, k4 = fl & 7;
            float4 v = *(const float4*)(conn + (size_t)(row0 + r) * 128 + k0 + k4 * 4);
            int base = ((r >> 4) * 64 + (r & 15) + ((k4 >> 1) << 4)) * 8 + (k4 & 1) * 4;
            u16 hx, lx, hy, ly, hz, lz, hw, lw;
            split2(v.x, hx, lx); split2(v.y, hy, ly);
            split2(v.z, hz, lz); split2(v.w, hw, lw);
            ushort4 ph; ph.x = hx; ph.y = hy; ph.z = hz; ph.w = hw;
            ushort4 pl; pl.x = lx; pl.y = ly; pl.z = lz; pl.w = lw;
            *(ushort4*)&Ah[base] = ph;
            *(ushort4*)&Al[base] = pl;
        }
#pragma unroll
        for (int hb = 0; hb < 2; hb++) {
            int kb = (t >> 5) * 4;
            int c0 = hb * 128 + (t & 31) * 4;
            const float* wp = WE + (size_t)(k0 + kb) * 256 + c0;
            float4 w0 = *(const float4*)(wp);
            float4 w1 = *(const float4*)(wp + 256);
            float4 w2 = *(const float4*)(wp + 512);
            float4 w3 = *(const float4*)(wp + 768);
#pragma unroll
            for (int j = 0; j < 4; j++) {
                float e0 = j == 0 ? w0.x : j == 1 ? w0.y : j == 2 ? w0.z : w0.w;
                float e1 = j == 0 ? w1.x : j == 1 ? w1.y : j == 2 ? w1.z : w1.w;
                float e2 = j == 0 ? w2.x : j == 1 ? w2.y : j == 2 ? w2.z : w2.w;
                float e3 = j == 0 ? w3.x : j == 1 ? w3.y : j == 2 ? w3.z : w3.w;
                int c = c0 + j;
                int base = ((c >> 4) * 64 + (c & 15) + ((kb >> 3) << 4)) * 8 + (kb & 4);
                u16 h0, l0, h1, l1, h2, l2, h3, l3;
                split2(e0, h0, l0); split2(e1, h1, l1);
                split2(e2, h2, l2); split2(e3, h3, l3);
                ushort4 ph; ph.x = h0; ph.y = h1; ph.z = h2; ph.w = h3;
                ushort4 pl; pl.x = l0; pl.y = l1; pl.z = l2; pl.w = l3;
                *(ushort4*)&Bh[base] = ph;
                *(ushort4*)&Bl[base] = pl;
            }
        }
        __syncthreads();
        bf16x8 ah[2], alo[2];
#pragma unroll
        for (int m = 0; m < 2; m++) {
            int rt = wr * 2 + m;
            ah[m] = *(const bf16x8*)&Ah[(rt * 64 + lane) * 8];
            alo[m] = *(const bf16x8*)&Al[(rt * 64 + lane) * 8];
        }
#pragma unroll
        for (int nn = 0; nn < 8; nn++) {
            int ct = (nn < 4) ? (wc * 4 + nn) : (8 + wc * 4 + (nn - 4));
            bf16x8 bh = *(const bf16x8*)&Bh[(ct * 64 + lane) * 8];
            bf16x8 bl = *(const bf16x8*)&Bl[(ct * 64 + lane) * 8];
#pragma unroll
            for (int m = 0; m < 2; m++) {
                acc[m][nn] = __builtin_amdgcn_mfma_f32_16x16x32_bf16(ah[m], bh, acc[m][nn], 0, 0, 0);
                acc[m][nn] = __builtin_amdgcn_mfma_f32_16x16x32_bf16(ah[m], bl, acc[m][nn], 0, 0, 0);
                acc[m][nn] = __builtin_amdgcn_mfma_f32_16x16x32_bf16(alo[m], bh, acc[m][nn], 0, 0, 0);
            }
        }
        __syncthreads();
    }

    float aw0 = Aw[c15 * 8 + wc * 4 + 0];
    float aw1 = Aw[c15 * 8 + wc * 4 + 1];
    float aw2 = Aw[c15 * 8 + wc * 4 + 2];
    float aw3 = Aw[c15 * 8 + wc * 4 + 3];

#pragma unroll
    for (int m = 0; m < 2; m++) {
#pragma unroll
        for (int r = 0; r < 4; r++) {
            int e = row0 + wr * 32 + m * 16 + lg * 4 + r;
            int dn = ei[e], sn = ei[NE + e];
            float sp0 = 0.f, sp1 = 0.f, sp2 = 0.f, sp3 = 0.f;
#pragma unroll
            for (int n = 0; n < 4; n++) {
                int j = wc * 64 + n * 16 + c15;
                float mv = Qh[(size_t)dn * 128 + j] + Kh[(size_t)sn * 128 + j];
                float cw = mv * acc[m][n][r];
                float ss = (cw > 0.f) ? sqrtf(cw) : ((cw < 0.f) ? -sqrtf(-cw) : 0.f);
                float v = fmaxf(ss + acc[m][4 + n][r], 0.f);
                conn_e[(size_t)e * 128 + j] = f2bf(v);
                float aw = n == 0 ? aw0 : n == 1 ? aw1 : n == 2 ? aw2 : aw3;
                float s = v * aw;
                s += __shfl_xor(s, 1);
                s += __shfl_xor(s, 2);
                s += __shfl_xor(s, 4);
                s += __shfl_xor(s, 8);
                if (n == 0) sp0 = s; else if (n == 1) sp1 = s; else if (n == 2) sp2 = s; else sp3 = s;
            }
            if (c15 == 0) {
                size_t sb = (size_t)e * 8 + wc * 4;
                scoreraw[sb + 0] = fminf(fmaxf(sp0, -5.f), 5.f);
                scoreraw[sb + 1] = fminf(fmaxf(sp1, -5.f), 5.f);
                scoreraw[sb + 2] = fminf(fmaxf(sp2, -5.f), 5.f);
                scoreraw[sb + 3] = fminf(fmaxf(sp3, -5.f), 5.f);
            }
        }
    }
}

// ---------------- per-node gather (unchanged)
__global__ void k_gather(const int* __restrict__ ei, const int* __restrict__ rowstart,
                         const int* __restrict__ csr, const float* __restrict__ scoreraw,
                         const u16* __restrict__ conn_e, const float* __restrict__ Vh,
                         const float* __restrict__ Qh, const float* __restrict__ Bw,
                         const float* __restrict__ logdeg, const float* __restrict__ deg_coef,
                         float* __restrict__ tout) {
    int n = blockIdx.x;
    int j = threadIdx.x;  // 0..127
    int h = j >> 4, d = j & 15;
    int rs = rowstart[n], re = rowstart[n + 1];

    float mx = -1e30f;
    for (int p = rs; p < re; p++) {
        int e = csr[p];
        mx = fmaxf(mx, scoreraw[(size_t)e * 8 + h]);
    }
    float ssum = 0.f, aggj = 0.f, rowvj = 0.f;
    for (int p = rs; p < re; p++) {
        int e = csr[p];
        float s = expf(scoreraw[(size_t)e * 8 + h] - mx);
        ssum += s;
        int sn = ei[NE + e];
        aggj = fmaf(Vh[(size_t)sn * 128 + j], s, aggj);
        rowvj = fmaf(bf2f(conn_e[(size_t)e * 128 + j]), s, rowvj);
    }
    float inv = 1.f / (ssum + 1e-16f);
    aggj *= inv;
    rowvj *= inv;

    __shared__ float rv[128];
    rv[j] = rowvj;
    __syncthreads();
    float ro = 0.f;
#pragma unroll
    for (int d2 = 0; d2 < 16; d2++) ro = fmaf(rv[h * 16 + d2], Bw[(d2 * 8 + h) * 16 + d], ro);

    float ha = Qh[(size_t)n * 128 + j] + aggj + ro;
    float ld = logdeg[n];
    tout[(size_t)n * 128 + j] = ha * (deg_coef[2 * j] + ld * deg_coef[2 * j + 1]);
}

// ---------------- LayerNorm(a + b) * g + be  -> out  (rows of 128)
__global__ void k_ln_res(const float* __restrict__ a, const float* __restrict__ b,
                         const float* __restrict__ g, const float* __restrict__ be,
                         float* __restrict__ out, int M) {
    int row = blockIdx.x * 4 + (threadIdx.x >> 6);
    int lane = threadIdx.x & 63;
    if (row >= M) return;
    size_t off = (size_t)row * 128 + lane * 2;
    float v0 = a[off] + b[off];
    float v1 = a[off + 1] + b[off + 1];
    float s = v0 + v1;
#pragma unroll
    for (int m = 1; m < 64; m <<= 1) s += __shfl_xor(s, m);
    float mean = s * (1.f / 128.f);
    float d0 = v0 - mean, d1 = v1 - mean;
    float q = d0 * d0 + d1 * d1;
#pragma unroll
    for (int m = 1; m < 64; m <<= 1) q += __shfl_xor(q, m);
    float rstd = rsqrtf(q * (1.f / 128.f) + 1e-5f);
    out[off] = d0 * rstd * g[lane * 2] + be[lane * 2];
    out[off + 1] = d1 * rstd * g[lane * 2 + 1] + be[lane * 2 + 1];
}

// ---------------- fused edge out (MFMA): e = LN1e(conn + conn_e@Eo_w + Eo_b)
// A = conn_e already bf16 (exact) -> 2 passes (A*Bh + A*Bl).
// wave tile 16 rows x 128 cols so each row's LN stays within one wave.
__global__ __launch_bounds__(256) void k_edge_out(
    const u16* __restrict__ conn_e, const float* __restrict__ Eo_w,
    const float* __restrict__ Eo_b, const float* __restrict__ conn,
    const float* __restrict__ g, const float* __restrict__ be,
    float* __restrict__ eout) {
    __shared__ __align__(16) u16 Asm[4 * 64 * 8];
    __shared__ __align__(16) u16 Bh[8 * 64 * 8], Bl[8 * 64 * 8];
    const int t = threadIdx.x;
    const int lane = t & 63, wid = t >> 6;
    const int c15 = lane & 15, lg = lane >> 4;
    const int row0 = blockIdx.x * 64;

    f32x4 acc[8];
#pragma unroll
    for (int n = 0; n < 8; n++) acc[n] = (f32x4){0.f, 0.f, 0.f, 0.f};

    for (int k0 = 0; k0 < 128; k0 += 32) {
        {
            int r = t >> 2, gq = t & 3;
            uint4 u = *(const uint4*)(conn_e + (size_t)(row0 + r) * 128 + k0 + gq * 8);
            int base = ((r >> 4) * 64 + (r & 15) + (gq << 4)) * 8;
            *(uint4*)&Asm[base] = u;
        }
        {
            int kb = (t >> 5) * 4;
            int c0 = (t & 31) * 4;
            const float* wp = Eo_w + (size_t)(k0 + kb) * 128 + c0;
            float4 w0 = *(const float4*)(wp);
            float4 w1 = *(const float4*)(wp + 128);
            float4 w2 = *(const float4*)(wp + 256);
            float4 w3 = *(const float4*)(wp + 384);
#pragma unroll
            for (int j = 0; j < 4; j++) {
                float e0 = j == 0 ? w0.x : j == 1 ? w0.y : j == 2 ? w0.z : w0.w;
                float e1 = j == 0 ? w1.x : j == 1 ? w1.y : j == 2 ? w1.z : w1.w;
                float e2 = j == 0 ? w2.x : j == 1 ? w2.y : j == 2 ? w2.z : w2.w;
                float e3 = j == 0 ? w3.x : j == 1 ? w3.y : j == 2 ? w3.z : w3.w;
                int c = c0 + j;
                int base = ((c >> 4) * 64 + (c & 15) + ((kb >> 3) << 4)) * 8 + (kb & 4);
                u16 h0, l0, h1, l1, h2, l2, h3, l3;
                split2(e0, h0, l0); split2(e1, h1, l1);
                split2(e2, h2, l2); split2(e3, h3, l3);
                ushort4 ph; ph.x = h0; ph.y = h1; ph.z = h2; ph.w = h3;
                ushort4 pl; pl.x = l0; pl.y = l1; pl.z = l2; pl.w = l3;
                *(ushort4*)&Bh[base] = ph;
                *(ushort4*)&Bl[base] = pl;
            }
        }
        __syncthreads();
        bf16x8 a = *(const bf16x8*)&Asm[(wid * 64 + lane) * 8];
#pragma unroll
        for (int n = 0; n < 8; n++) {
            bf16x8 bh = *(const bf16x8*)&Bh[(n * 64 + lane) * 8];
            bf16x8 bl = *(const bf16x8*)&Bl[(n * 64 + lane) * 8];
            acc[n] = __builtin_amdgcn_mfma_f32_16x16x32_bf16(a, bh, acc[n], 0, 0, 0);
            acc[n] = __builtin_amdgcn_mfma_f32_16x16x32_bf16(a, bl, acc[n], 0, 0, 0);
        }
        __syncthreads();
    }

    float ebv[8], gv[8], bev[8];
#pragma unroll
    for (int n = 0; n < 8; n++) {
        int col = n * 16 + c15;
        ebv[n] = Eo_b[col];
        gv[n] = g[col];
        bev[n] = be[col];
    }
#pragma unroll
    for (int r = 0; r < 4; r++) {
        int e = row0 + wid * 16 + lg * 4 + r;
        float v[8];
        float s1 = 0.f, s2 = 0.f;
#pragma unroll
        for (int n = 0; n < 8; n++) {
            int col = n * 16 + c15;
            float x = acc[n][r] + ebv[n] + conn[(size_t)e * 128 + col];
            v[n] = x;
            s1 += x;
            s2 += x * x;
        }
#pragma unroll
        for (int msk = 1; msk < 16; msk <<= 1) {
            s1 += __shfl_xor(s1, msk);
            s2 += __shfl_xor(s2, msk);
        }
        float mean = s1 * (1.f / 128.f);
        float var = s2 * (1.f / 128.f) - mean * mean;
        float rstd = rsqrtf(var + 1e-5f);
#pragma unroll
        for (int n = 0; n < 8; n++) {
            int col = n * 16 + c15;
            eout[(size_t)e * 128 + col] = (v[n] - mean) * rstd * gv[n] + bev[n];
        }
    }
}

extern "C" void kernel_launch(void* const* d_in, const int* in_sizes, int n_in,
                              void* d_out, int out_size, void* d_ws, size_t ws_size,
                              hipStream_t stream) {
    const float* x = (const float*)d_in[0];
    const float* conn = (const float*)d_in[1];
    const float* log_deg = (const float*)d_in[2];
    const int* ei = (const int*)d_in[3];
    const float* WQ = (const float*)d_in[4];
    const float* WK = (const float*)d_in[5];
    const float* WV = (const float*)d_in[6];
    const float* WE = (const float*)d_in[7];
    const float* Aw = (const float*)d_in[8];
    const float* Bw = (const float*)d_in[9];
    const float* Ho_w = (const float*)d_in[10];
    const float* Ho_b = (const float*)d_in[11];
    const float* Eo_w = (const float*)d_in[12];
    const float* Eo_b = (const float*)d_in[13];
    const float* deg_coef = (const float*)d_in[14];
    const float* ln1h_g = (const float*)d_in[15];
    const float* ln1h_b = (const float*)d_in[16];
    const float* ln1e_g = (const float*)d_in[17];
    const float* ln1e_b = (const float*)d_in[18];
    const float* ln2h_g = (const float*)d_in[19];
    const float* ln2h_b = (const float*)d_in[20];
    const float* W1 = (const float*)d_in[21];
    const float* b1 = (const float*)d_in[22];
    const float* W2 = (const float*)d_in[23];
    const float* b2 = (const float*)d_in[24];

    // workspace layout
    float* fbase = (float*)d_ws;
    float* Qh = fbase;
    float* Kh = Qh + (size_t)NN * HIDC;
    float* Vh = Kh + (size_t)NN * HIDC;
    float* tbuf = Vh + (size_t)NN * HIDC;
    float* h1 = tbuf + (size_t)NN * HIDC;
    float* scoreraw = h1 + (size_t)NN * HIDC;
    u16* conn_e = (u16*)(scoreraw + (size_t)NE * NH);
    int* deg = (int*)(conn_e + (size_t)NE * HIDC);
    int* rowstart = deg + NN;
    int* cursor = rowstart + NN + 1;
    int* csr = cursor + NN;
    float* f1 = (float*)conn_e;  // reused after edge_out
    float* u_h = Vh;             // reused after gather
    float* u2 = Qh;              // reused after gather

    float* out_h = (float*)d_out;
    float* out_e = out_h + (size_t)NN * HIDC;

    const int gN64 = (NN + 63) / 64;
    const int gE64 = NE / 64;

    k_init<<<(NN + 255) / 256, 256, 0, stream>>>(deg, cursor);
    k_count<<<(NE + 255) / 256, 256, 0, stream>>>(ei, deg);
    k_scan<<<1, 1024, 0, stream>>>(deg, rowstart);
    k_fill<<<(NE + 255) / 256, 256, 0, stream>>>(ei, rowstart, cursor, csr);

    k_gemm<128, 128, false><<<gN64, 256, 0, stream>>>(x, WQ, nullptr, Qh, NN);
    k_gemm<128, 128, false><<<gN64, 256, 0, stream>>>(x, WK, nullptr, Kh, NN);
    k_gemm<128, 128, false><<<gN64, 256, 0, stream>>>(x, WV, nullptr, Vh, NN);

    k_edge_pre<<<gE64, 256, 0, stream>>>(conn, WE, Qh, Kh, ei, Aw, conn_e, scoreraw);

    k_gather<<<NN, 128, 0, stream>>>(ei, rowstart, csr, scoreraw, conn_e, Vh, Qh, Bw,
                                     log_deg, deg_coef, tbuf);

    k_gemm<128, 128, false><<<gN64, 256, 0, stream>>>(tbuf, Ho_w, Ho_b, u_h, NN);
    k_ln_res<<<(NN + 3) / 4, 256, 0, stream>>>(u_h, x, ln1h_g, ln1h_b, h1, NN);

    k_edge_out<<<gE64, 256, 0, stream>>>(conn_e, Eo_w, Eo_b, conn, ln1e_g, ln1e_b, out_e);

    k_gemm<256, 128, true><<<gN64, 256, 0, stream>>>(h1, W1, b1, f1, NN);
    k_gemm<128, 256, false><<<gN64, 256, 0, stream>>>(f1, W2, b2, u2, NN);
    k_ln_res<<<(NN + 3) / 4, 256, 0, stream>>>(u2, h1, ln2h_g, ln2h_b, out_h, NN);
}

// Round 2
// 1568.775 us; speedup vs baseline: 1.0469x; 1.0469x over previous
//
#include <hip/hip_runtime.h>
#include <hip/hip_bf16.h>

#define NN 50000
#define NE 600000
#define HIDC 128
#define NH 8
#define DH 16

typedef unsigned short u16;
typedef __attribute__((ext_vector_type(8))) short bf16x8;
typedef __attribute__((ext_vector_type(4))) float f32x4;

static __device__ __forceinline__ float bf2f(u16 u) {
    unsigned int x = ((unsigned int)u) << 16;
    return __uint_as_float(x);
}
static __device__ __forceinline__ u16 f2bf(float f) {
    unsigned int x = __float_as_uint(f);
    unsigned int r = (x + 0x7fffu + ((x >> 16) & 1u)) >> 16;
    return (u16)r;
}
static __device__ __forceinline__ void split2(float v, u16& h, u16& l) {
    h = f2bf(v);
    l = f2bf(v - bf2f(h));
}

// ---------------- CSR build ----------------
__global__ void k_init(int* deg, int* cursor) {
    int i = blockIdx.x * blockDim.x + threadIdx.x;
    if (i < NN) { deg[i] = 0; cursor[i] = 0; }
}

__global__ void k_count(const int* __restrict__ ei, int* __restrict__ deg) {
    int e = blockIdx.x * blockDim.x + threadIdx.x;
    if (e < NE) atomicAdd(&deg[ei[e]], 1);
}

// single-block scan, 1024 threads, 4 elems/thread/chunk, shfl-based
__global__ void k_scan(const int* __restrict__ deg, int* __restrict__ rowstart) {
    __shared__ int warpsum[16];
    __shared__ int chunkcarry;
    int t = threadIdx.x;
    int lane = t & 63, w = t >> 6;
    if (t == 0) { chunkcarry = 0; rowstart[0] = 0; }
    __syncthreads();
    for (int base = 0; base < NN; base += 4096) {
        int idx = base + t * 4;
        int v0 = (idx + 0 < NN) ? deg[idx + 0] : 0;
        int v1 = (idx + 1 < NN) ? deg[idx + 1] : 0;
        int v2 = (idx + 2 < NN) ? deg[idx + 2] : 0;
        int v3 = (idx + 3 < NN) ? deg[idx + 3] : 0;
        int s0 = v0, s1 = s0 + v1, s2 = s1 + v2, s3 = s2 + v3;
        int tot = s3;
        int sc = tot;
#pragma unroll
        for (int off = 1; off < 64; off <<= 1) {
            int u = __shfl_up(sc, off);
            if (lane >= off) sc += u;
        }
        if (lane == 63) warpsum[w] = sc;
        __syncthreads();
        int wpre = 0;
        for (int i = 0; i < w; i++) wpre += warpsum[i];
        int carry = chunkcarry;
        __syncthreads();
        int pre = carry + wpre + (sc - tot);
        if (idx + 0 < NN) rowstart[idx + 1] = pre + s0;
        if (idx + 1 < NN) rowstart[idx + 2] = pre + s1;
        if (idx + 2 < NN) rowstart[idx + 3] = pre + s2;
        if (idx + 3 < NN) rowstart[idx + 4] = pre + s3;
        if (t == 1023) chunkcarry = carry + wpre + sc;
        __syncthreads();
    }
}

__global__ void k_fill(const int* __restrict__ ei, const int* __restrict__ rowstart,
                       int* __restrict__ cursor, int* __restrict__ csr) {
    int e = blockIdx.x * blockDim.x + threadIdx.x;
    if (e < NE) {
        int d = ei[e];
        int slot = atomicAdd(&cursor[d], 1);
        csr[rowstart[d] + slot] = e;
    }
}

// ---------------- weight preconvert: W[K x NC] f32 -> bf16 hi/lo in MFMA
// fragment order: hi[(kt*NCT+ct)*512 + l*8 + j] = W[kt*32 + (l>>4)*8 + j][ct*16 + (l&15)]
__global__ void k_conv_w(const float* __restrict__ W, u16* __restrict__ hi,
                         u16* __restrict__ lo, int K, int NC) {
    int idx = blockIdx.x * blockDim.x + threadIdx.x;
    int total = (K >> 5) * (NC >> 4) * 64;
    if (idx >= total) return;
    int l = idx & 63;
    int f = idx >> 6;
    int NCT = NC >> 4;
    int kt = f / NCT, ct = f - kt * NCT;
    int col = ct * 16 + (l & 15);
    int krow = kt * 32 + (l >> 4) * 8;
    u16 ph[8], pl[8];
#pragma unroll
    for (int j = 0; j < 8; j++) {
        float v = W[(size_t)(krow + j) * NC + col];
        split2(v, ph[j], pl[j]);
    }
    *(uint4*)(hi + (size_t)idx * 8) = *(uint4*)ph;
    *(uint4*)(lo + (size_t)idx * 8) = *(uint4*)pl;
}

// ---------------- MFMA GEMM: C[M x NC] = A[M x K] @ W[K x NC] (+bias)(+relu)
// A fp32 -> bf16 hi/lo split in-kernel (fragment-aligned staging, conflict-free);
// B preconverted bf16 hi/lo, fragment-ordered: pure uint4 copy to LDS.
// 3 MFMA passes (Ah*Bh + Ah*Bl + Al*Bh ~ fp32 accuracy).
template <int NC, int K, bool RELU>
__global__ __launch_bounds__(256) void k_gemm(const float* __restrict__ A,
                                              const u16* __restrict__ Wh,
                                              const u16* __restrict__ Wl,
                                              const float* __restrict__ bias,
                                              float* __restrict__ C, int M) {
    constexpr int NCT = NC / 16;
    constexpr int NCT_W = NC / 32;
    __shared__ __align__(16) u16 Ah[4 * 64 * 8], Al[4 * 64 * 8];
    __shared__ __align__(16) u16 Bh[NCT * 64 * 8], Bl[NCT * 64 * 8];

    const int t = threadIdx.x;
    const int lane = t & 63, wid = t >> 6;
    const int wr = wid >> 1, wc = wid & 1;
    const int c15 = lane & 15, lg = lane >> 4;
    const int row0 = blockIdx.x * 64;

    f32x4 acc[2][NCT_W];
#pragma unroll
    for (int m = 0; m < 2; m++)
#pragma unroll
        for (int n = 0; n < NCT_W; n++) acc[m][n] = (f32x4){0.f, 0.f, 0.f, 0.f};

    for (int kt = 0; kt < K / 32; kt++) {
        // stage A: thread = (row r, k-octet ko); one 16B hi + 16B lo write, dense.
        {
            int r = t >> 2, ko = t & 3;
            int row = row0 + r;
            float4 v0 = make_float4(0.f, 0.f, 0.f, 0.f), v1 = v0;
            if (row < M) {
                const float* ap = A + (size_t)row * K + kt * 32 + ko * 8;
                v0 = *(const float4*)ap;
                v1 = *(const float4*)(ap + 4);
            }
            u16 ph[8], pl[8];
            split2(v0.x, ph[0], pl[0]); split2(v0.y, ph[1], pl[1]);
            split2(v0.z, ph[2], pl[2]); split2(v0.w, ph[3], pl[3]);
            split2(v1.x, ph[4], pl[4]); split2(v1.y, ph[5], pl[5]);
            split2(v1.z, ph[6], pl[6]); split2(v1.w, ph[7], pl[7]);
            int ab = ((r >> 4) * 64 + ko * 16 + (r & 15)) * 8;
            *(uint4*)&Ah[ab] = *(uint4*)ph;
            *(uint4*)&Al[ab] = *(uint4*)pl;
        }
        // stage B: linear fragment-ordered copy
        {
            const u16* bhp = Wh + (size_t)kt * (NCT * 512);
            const u16* blp = Wl + (size_t)kt * (NCT * 512);
#pragma unroll
            for (int i = 0; i < NCT / 4; i++) {
                int o = (t + i * 256) * 8;
                *(uint4*)&Bh[o] = *(const uint4*)&bhp[o];
                *(uint4*)&Bl[o] = *(const uint4*)&blp[o];
            }
        }
        __syncthreads();
        bf16x8 ah[2], alo[2];
#pragma unroll
        for (int m = 0; m < 2; m++) {
            int rt = wr * 2 + m;
            ah[m] = *(const bf16x8*)&Ah[(rt * 64 + lane) * 8];
            alo[m] = *(const bf16x8*)&Al[(rt * 64 + lane) * 8];
        }
#pragma unroll
        for (int n = 0; n < NCT_W; n++) {
            int ct = wc * NCT_W + n;
            bf16x8 bh = *(const bf16x8*)&Bh[(ct * 64 + lane) * 8];
            bf16x8 bl = *(const bf16x8*)&Bl[(ct * 64 + lane) * 8];
#pragma unroll
            for (int m = 0; m < 2; m++) {
                acc[m][n] = __builtin_amdgcn_mfma_f32_16x16x32_bf16(ah[m], bh, acc[m][n], 0, 0, 0);
                acc[m][n] = __builtin_amdgcn_mfma_f32_16x16x32_bf16(ah[m], bl, acc[m][n], 0, 0, 0);
                acc[m][n] = __builtin_amdgcn_mfma_f32_16x16x32_bf16(alo[m], bh, acc[m][n], 0, 0, 0);
            }
        }
        __syncthreads();
    }
    // epilogue: D col = lane&15, row = 4*(lane>>4)+reg
#pragma unroll
    for (int m = 0; m < 2; m++) {
        int rbase = row0 + wr * 32 + m * 16 + lg * 4;
#pragma unroll
        for (int n = 0; n < NCT_W; n++) {
            int col = wc * (NCT_W * 16) + n * 16 + c15;
            float bv = bias ? bias[col] : 0.f;
#pragma unroll
            for (int r = 0; r < 4; r++) {
                int row = rbase + r;
                if (row < M) {
                    float o = acc[m][n][r] + bv;
                    if (RELU) o = fmaxf(o, 0.f);
                    C[(size_t)row * NC + col] = o;
                }
            }
        }
    }
}

// ---------------- fused edge pre (MFMA): Eh = conn@WE (K=128, NC=256), epilogue:
// conn_e = relu(signed_sqrt((Qh[dst]+Kh[src])*Ew)+Eb) -> bf16; clamped score per head.
__global__ __launch_bounds__(256) void k_edge_pre(
    const float* __restrict__ conn, const u16* __restrict__ WEh, const u16* __restrict__ WEl,
    const float* __restrict__ Qh, const float* __restrict__ Kh,
    const int* __restrict__ ei, const float* __restrict__ Aw,
    u16* __restrict__ conn_e, float* __restrict__ scoreraw) {
    __shared__ __align__(16) u16 Ah[4 * 64 * 8], Al[4 * 64 * 8];
    __shared__ __align__(16) u16 Bh[16 * 64 * 8], Bl[16 * 64 * 8];
    const int t = threadIdx.x;
    const int lane = t & 63, wid = t >> 6;
    const int wr = wid >> 1, wc = wid & 1;
    const int c15 = lane & 15, lg = lane >> 4;
    const int row0 = blockIdx.x * 64;

    f32x4 acc[2][8];
#pragma unroll
    for (int m = 0; m < 2; m++)
#pragma unroll
        for (int n = 0; n < 8; n++) acc[m][n] = (f32x4){0.f, 0.f, 0.f, 0.f};

    for (int kt = 0; kt < 4; kt++) {
        {
            int r = t >> 2, ko = t & 3;
            const float* ap = conn + (size_t)(row0 + r) * 128 + kt * 32 + ko * 8;
            float4 v0 = *(const float4*)ap;
            float4 v1 = *(const float4*)(ap + 4);
            u16 ph[8], pl[8];
            split2(v0.x, ph[0], pl[0]); split2(v0.y, ph[1], pl[1]);
            split2(v0.z, ph[2], pl[2]); split2(v0.w, ph[3], pl[3]);
            split2(v1.x, ph[4], pl[4]); split2(v1.y, ph[5], pl[5]);
            split2(v1.z, ph[6], pl[6]); split2(v1.w, ph[7], pl[7]);
            int ab = ((r >> 4) * 64 + ko * 16 + (r & 15)) * 8;
            *(uint4*)&Ah[ab] = *(uint4*)ph;
            *(uint4*)&Al[ab] = *(uint4*)pl;
        }
        {
            const u16* bhp = WEh + (size_t)kt * (16 * 512);
            const u16* blp = WEl + (size_t)kt * (16 * 512);
#pragma unroll
            for (int i = 0; i < 4; i++) {
                int o = (t + i * 256) * 8;
                *(uint4*)&Bh[o] = *(const uint4*)&bhp[o];
                *(uint4*)&Bl[o] = *(const uint4*)&blp[o];
            }
        }
        __syncthreads();
        bf16x8 ah[2], alo[2];
#pragma unroll
        for (int m = 0; m < 2; m++) {
            int rt = wr * 2 + m;
            ah[m] = *(const bf16x8*)&Ah[(rt * 64 + lane) * 8];
            alo[m] = *(const bf16x8*)&Al[(rt * 64 + lane) * 8];
        }
#pragma unroll
        for (int nn = 0; nn < 8; nn++) {
            int ct = (nn < 4) ? (wc * 4 + nn) : (8 + wc * 4 + (nn - 4));
            bf16x8 bh = *(const bf16x8*)&Bh[(ct * 64 + lane) * 8];
            bf16x8 bl = *(const bf16x8*)&Bl[(ct * 64 + lane) * 8];
#pragma unroll
            for (int m = 0; m < 2; m++) {
                acc[m][nn] = __builtin_amdgcn_mfma_f32_16x16x32_bf16(ah[m], bh, acc[m][nn], 0, 0, 0);
                acc[m][nn] = __builtin_amdgcn_mfma_f32_16x16x32_bf16(ah[m], bl, acc[m][nn], 0, 0, 0);
                acc[m][nn] = __builtin_amdgcn_mfma_f32_16x16x32_bf16(alo[m], bh, acc[m][nn], 0, 0, 0);
            }
        }
        __syncthreads();
    }

    float aw0 = Aw[c15 * 8 + wc * 4 + 0];
    float aw1 = Aw[c15 * 8 + wc * 4 + 1];
    float aw2 = Aw[c15 * 8 + wc * 4 + 2];
    float aw3 = Aw[c15 * 8 + wc * 4 + 3];

#pragma unroll
    for (int m = 0; m < 2; m++) {
#pragma unroll
        for (int r = 0; r < 4; r++) {
            int e = row0 + wr * 32 + m * 16 + lg * 4 + r;
            int dn = ei[e], sn = ei[NE + e];
            float sp0 = 0.f, sp1 = 0.f, sp2 = 0.f, sp3 = 0.f;
#pragma unroll
            for (int n = 0; n < 4; n++) {
                int j = wc * 64 + n * 16 + c15;
                float mv = Qh[(size_t)dn * 128 + j] + Kh[(size_t)sn * 128 + j];
                float cw = mv * acc[m][n][r];
                float ss = (cw > 0.f) ? sqrtf(cw) : ((cw < 0.f) ? -sqrtf(-cw) : 0.f);
                float v = fmaxf(ss + acc[m][4 + n][r], 0.f);
                conn_e[(size_t)e * 128 + j] = f2bf(v);
                float aw = n == 0 ? aw0 : n == 1 ? aw1 : n == 2 ? aw2 : aw3;
                float s = v * aw;
                s += __shfl_xor(s, 1);
                s += __shfl_xor(s, 2);
                s += __shfl_xor(s, 4);
                s += __shfl_xor(s, 8);
                if (n == 0) sp0 = s; else if (n == 1) sp1 = s; else if (n == 2) sp2 = s; else sp3 = s;
            }
            if (c15 == 0) {
                size_t sb = (size_t)e * 8 + wc * 4;
                scoreraw[sb + 0] = fminf(fmaxf(sp0, -5.f), 5.f);
                scoreraw[sb + 1] = fminf(fmaxf(sp1, -5.f), 5.f);
                scoreraw[sb + 2] = fminf(fmaxf(sp2, -5.f), 5.f);
                scoreraw[sb + 3] = fminf(fmaxf(sp3, -5.f), 5.f);
            }
        }
    }
}

// ---------------- per-node gather: 2 nodes per block (256 threads)
__global__ void k_gather(const int* __restrict__ ei, const int* __restrict__ rowstart,
                         const int* __restrict__ csr, const float* __restrict__ scoreraw,
                         const u16* __restrict__ conn_e, const float* __restrict__ Vh,
                         const float* __restrict__ Qh, const float* __restrict__ Bw,
                         const float* __restrict__ logdeg, const float* __restrict__ deg_coef,
                         float* __restrict__ tout) {
    int half = threadIdx.x >> 7;
    int n = blockIdx.x * 2 + half;
    int j = threadIdx.x & 127;
    int h = j >> 4, d = j & 15;
    int rs = rowstart[n], re = rowstart[n + 1];

    float mx = -1e30f;
    for (int p = rs; p < re; p++) {
        int e = csr[p];
        mx = fmaxf(mx, scoreraw[(size_t)e * 8 + h]);
    }
    float ssum = 0.f, aggj = 0.f, rowvj = 0.f;
    for (int p = rs; p < re; p++) {
        int e = csr[p];
        float s = expf(scoreraw[(size_t)e * 8 + h] - mx);
        ssum += s;
        int sn = ei[NE + e];
        aggj = fmaf(Vh[(size_t)sn * 128 + j], s, aggj);
        rowvj = fmaf(bf2f(conn_e[(size_t)e * 128 + j]), s, rowvj);
    }
    float inv = 1.f / (ssum + 1e-16f);
    aggj *= inv;
    rowvj *= inv;

    __shared__ float rv[2][128];
    rv[half][j] = rowvj;
    __syncthreads();
    float ro = 0.f;
#pragma unroll
    for (int d2 = 0; d2 < 16; d2++) ro = fmaf(rv[half][h * 16 + d2], Bw[(d2 * 8 + h) * 16 + d], ro);

    float ha = Qh[(size_t)n * 128 + j] + aggj + ro;
    float ld = logdeg[n];
    tout[(size_t)n * 128 + j] = ha * (deg_coef[2 * j] + ld * deg_coef[2 * j + 1]);
}

// ---------------- LayerNorm(a + b) * g + be  -> out  (rows of 128)
__global__ void k_ln_res(const float* __restrict__ a, const float* __restrict__ b,
                         const float* __restrict__ g, const float* __restrict__ be,
                         float* __restrict__ out, int M) {
    int row = blockIdx.x * 4 + (threadIdx.x >> 6);
    int lane = threadIdx.x & 63;
    if (row >= M) return;
    size_t off = (size_t)row * 128 + lane * 2;
    float v0 = a[off] + b[off];
    float v1 = a[off + 1] + b[off + 1];
    float s = v0 + v1;
#pragma unroll
    for (int m = 1; m < 64; m <<= 1) s += __shfl_xor(s, m);
    float mean = s * (1.f / 128.f);
    float d0 = v0 - mean, d1 = v1 - mean;
    float q = d0 * d0 + d1 * d1;
#pragma unroll
    for (int m = 1; m < 64; m <<= 1) q += __shfl_xor(q, m);
    float rstd = rsqrtf(q * (1.f / 128.f) + 1e-5f);
    out[off] = d0 * rstd * g[lane * 2] + be[lane * 2];
    out[off + 1] = d1 * rstd * g[lane * 2 + 1] + be[lane * 2 + 1];
}

// ---------------- fused edge out (MFMA): e = LN1e(conn + conn_e@Eo_w + Eo_b)
// A = conn_e already bf16 (exact) -> 2 passes (A*Bh + A*Bl).
__global__ __launch_bounds__(256) void k_edge_out(
    const u16* __restrict__ conn_e, const u16* __restrict__ Eoh, const u16* __restrict__ Eol,
    const float* __restrict__ Eo_b, const float* __restrict__ conn,
    const float* __restrict__ g, const float* __restrict__ be,
    float* __restrict__ eout) {
    __shared__ __align__(16) u16 Asm[4 * 64 * 8];
    __shared__ __align__(16) u16 Bh[8 * 64 * 8], Bl[8 * 64 * 8];
    const int t = threadIdx.x;
    const int lane = t & 63, wid = t >> 6;
    const int c15 = lane & 15, lg = lane >> 4;
    const int row0 = blockIdx.x * 64;

    f32x4 acc[8];
#pragma unroll
    for (int n = 0; n < 8; n++) acc[n] = (f32x4){0.f, 0.f, 0.f, 0.f};

    for (int kt = 0; kt < 4; kt++) {
        {
            int r = t >> 2, gq = t & 3;
            uint4 u = *(const uint4*)(conn_e + (size_t)(row0 + r) * 128 + kt * 32 + gq * 8);
            int base = ((r >> 4) * 64 + (r & 15) + (gq << 4)) * 8;
            *(uint4*)&Asm[base] = u;
        }
        {
            const u16* bhp = Eoh + (size_t)kt * (8 * 512);
            const u16* blp = Eol + (size_t)kt * (8 * 512);
#pragma unroll
            for (int i = 0; i < 2; i++) {
                int o = (t + i * 256) * 8;
                *(uint4*)&Bh[o] = *(const uint4*)&bhp[o];
                *(uint4*)&Bl[o] = *(const uint4*)&blp[o];
            }
        }
        __syncthreads();
        bf16x8 a = *(const bf16x8*)&Asm[(wid * 64 + lane) * 8];
#pragma unroll
        for (int n = 0; n < 8; n++) {
            bf16x8 bh = *(const bf16x8*)&Bh[(n * 64 + lane) * 8];
            bf16x8 bl = *(const bf16x8*)&Bl[(n * 64 + lane) * 8];
            acc[n] = __builtin_amdgcn_mfma_f32_16x16x32_bf16(a, bh, acc[n], 0, 0, 0);
            acc[n] = __builtin_amdgcn_mfma_f32_16x16x32_bf16(a, bl, acc[n], 0, 0, 0);
        }
        __syncthreads();
    }

    float ebv[8], gv[8], bev[8];
#pragma unroll
    for (int n = 0; n < 8; n++) {
        int col = n * 16 + c15;
        ebv[n] = Eo_b[col];
        gv[n] = g[col];
        bev[n] = be[col];
    }
#pragma unroll
    for (int r = 0; r < 4; r++) {
        int e = row0 + wid * 16 + lg * 4 + r;
        float v[8];
        float s1 = 0.f, s2 = 0.f;
#pragma unroll
        for (int n = 0; n < 8; n++) {
            int col = n * 16 + c15;
            float x = acc[n][r] + ebv[n] + conn[(size_t)e * 128 + col];
            v[n] = x;
            s1 += x;
            s2 += x * x;
        }
#pragma unroll
        for (int msk = 1; msk < 16; msk <<= 1) {
            s1 += __shfl_xor(s1, msk);
            s2 += __shfl_xor(s2, msk);
        }
        float mean = s1 * (1.f / 128.f);
        float var = s2 * (1.f / 128.f) - mean * mean;
        float rstd = rsqrtf(var + 1e-5f);
#pragma unroll
        for (int n = 0; n < 8; n++) {
            int col = n * 16 + c15;
            eout[(size_t)e * 128 + col] = (v[n] - mean) * rstd * gv[n] + bev[n];
        }
    }
}

extern "C" void kernel_launch(void* const* d_in, const int* in_sizes, int n_in,
                              void* d_out, int out_size, void* d_ws, size_t ws_size,
                              hipStream_t stream) {
    const float* x = (const float*)d_in[0];
    const float* conn = (const float*)d_in[1];
    const float* log_deg = (const float*)d_in[2];
    const int* ei = (const int*)d_in[3];
    const float* WQ = (const float*)d_in[4];
    const float* WK = (const float*)d_in[5];
    const float* WV = (const float*)d_in[6];
    const float* WE = (const float*)d_in[7];
    const float* Aw = (const float*)d_in[8];
    const float* Bw = (const float*)d_in[9];
    const float* Ho_w = (const float*)d_in[10];
    const float* Ho_b = (const float*)d_in[11];
    const float* Eo_w = (const float*)d_in[12];
    const float* Eo_b = (const float*)d_in[13];
    const float* deg_coef = (const float*)d_in[14];
    const float* ln1h_g = (const float*)d_in[15];
    const float* ln1h_b = (const float*)d_in[16];
    const float* ln1e_g = (const float*)d_in[17];
    const float* ln1e_b = (const float*)d_in[18];
    const float* ln2h_g = (const float*)d_in[19];
    const float* ln2h_b = (const float*)d_in[20];
    const float* W1 = (const float*)d_in[21];
    const float* b1 = (const float*)d_in[22];
    const float* W2 = (const float*)d_in[23];
    const float* b2 = (const float*)d_in[24];

    // workspace layout
    float* fbase = (float*)d_ws;
    float* Qh = fbase;
    float* Kh = Qh + (size_t)NN * HIDC;
    float* Vh = Kh + (size_t)NN * HIDC;
    float* tbuf = Vh + (size_t)NN * HIDC;
    float* h1 = tbuf + (size_t)NN * HIDC;
    float* scoreraw = h1 + (size_t)NN * HIDC;
    u16* conn_e = (u16*)(scoreraw + (size_t)NE * NH);
    int* deg = (int*)(conn_e + (size_t)NE * HIDC);
    int* rowstart = deg + NN;
    int* cursor = rowstart + NN + 1;
    int* csr = cursor + NN;
    float* f1 = (float*)conn_e;  // reused after edge_out
    float* u_h = Vh;             // reused after gather
    float* u2 = Qh;              // reused after gather

    // preconverted weights (bf16 hi/lo, fragment order), 16B-aligned
    u16* wbuf = (u16*)(((uintptr_t)(csr + NE) + 15) & ~(uintptr_t)15);
    u16* WQh = wbuf;            u16* WQl = WQh + 16384;
    u16* WKh = WQl + 16384;     u16* WKl = WKh + 16384;
    u16* WVh = WKl + 16384;     u16* WVl = WVh + 16384;
    u16* WEh = WVl + 16384;     u16* WEl = WEh + 32768;
    u16* Hoh = WEl + 32768;     u16* Hol = Hoh + 16384;
    u16* Eoh = Hol + 16384;     u16* Eol = Eoh + 16384;
    u16* W1h = Eol + 16384;     u16* W1l = W1h + 32768;
    u16* W2h = W1l + 32768;     u16* W2l = W2h + 32768;

    float* out_h = (float*)d_out;
    float* out_e = out_h + (size_t)NN * HIDC;

    const int gN64 = (NN + 63) / 64;
    const int gE64 = NE / 64;

    // weight preconversion (tiny)
    k_conv_w<<<(2048 + 255) / 256, 256, 0, stream>>>(WQ, WQh, WQl, 128, 128);
    k_conv_w<<<(2048 + 255) / 256, 256, 0, stream>>>(WK, WKh, WKl, 128, 128);
    k_conv_w<<<(2048 + 255) / 256, 256, 0, stream>>>(WV, WVh, WVl, 128, 128);
    k_conv_w<<<(4096 + 255) / 256, 256, 0, stream>>>(WE, WEh, WEl, 128, 256);
    k_conv_w<<<(2048 + 255) / 256, 256, 0, stream>>>(Ho_w, Hoh, Hol, 128, 128);
    k_conv_w<<<(2048 + 255) / 256, 256, 0, stream>>>(Eo_w, Eoh, Eol, 128, 128);
    k_conv_w<<<(4096 + 255) / 256, 256, 0, stream>>>(W1, W1h, W1l, 128, 256);
    k_conv_w<<<(4096 + 255) / 256, 256, 0, stream>>>(W2, W2h, W2l, 256, 128);

    k_init<<<(NN + 255) / 256, 256, 0, stream>>>(deg, cursor);
    k_count<<<(NE + 255) / 256, 256, 0, stream>>>(ei, deg);
    k_scan<<<1, 1024, 0, stream>>>(deg, rowstart);
    k_fill<<<(NE + 255) / 256, 256, 0, stream>>>(ei, rowstart, cursor, csr);

    k_gemm<128, 128, false><<<gN64, 256, 0, stream>>>(x, WQh, WQl, nullptr, Qh, NN);
    k_gemm<128, 128, false><<<gN64, 256, 0, stream>>>(x, WKh, WKl, nullptr, Kh, NN);
    k_gemm<128, 128, false><<<gN64, 256, 0, stream>>>(x, WVh, WVl, nullptr, Vh, NN);

    k_edge_pre<<<gE64, 256, 0, stream>>>(conn, WEh, WEl, Qh, Kh, ei, Aw, conn_e, scoreraw);

    k_gather<<<NN / 2, 256, 0, stream>>>(ei, rowstart, csr, scoreraw, conn_e, Vh, Qh, Bw,
                                         log_deg, deg_coef, tbuf);

    k_gemm<128, 128, false><<<gN64, 256, 0, stream>>>(tbuf, Hoh, Hol, Ho_b, u_h, NN);
    k_ln_res<<<(NN + 3) / 4, 256, 0, stream>>>(u_h, x, ln1h_g, ln1h_b, h1, NN);

    k_edge_out<<<gE64, 256, 0, stream>>>(conn_e, Eoh, Eol, Eo_b, conn, ln1e_g, ln1e_b, out_e);

    k_gemm<256, 128, true><<<gN64, 256, 0, stream>>>(h1, W1h, W1l, b1, f1, NN);
    k_gemm<128, 256, false><<<gN64, 256, 0, stream>>>(f1, W2h, W2l, b2, u2, NN);
    k_ln_res<<<(NN + 3) / 4, 256, 0, stream>>>(u2, h1, ln2h_g, ln2h_b, out_h, NN);
}